// Round 1
// baseline (119.698 us; speedup 1.0000x reference)
//
#include <hip/hip_runtime.h>
#include <math.h>

// Problem constants (fixed by reference setup_inputs)
constexpr int B_ = 8;
constexpr int N_ = 2000;
constexpr int C_ = 81;
constexpr int BN = B_ * N_;

// d_out flat layout (element offsets), reference return order:
// nms_reg, nms_cls, rcnn_reg_adj, probs, reg_out, cls_out, keep
constexpr int O0 = 0;                 // nms_reg      B*N*4 = 64000
constexpr int O1 = 64000;             // nms_cls      B*N*2 = 32000
constexpr int O2 = 96000;             // rcnn_reg_adj B*N*4 = 64000
constexpr int O3 = 160000;            // probs        B*N*81 = 1296000
constexpr int O4 = 1456000;           // reg_out      B*N*4 = 64000
constexpr int O5 = 1520000;           // cls_out      B*N*81 = 1296000
constexpr int O6 = 2816000;           // keep         B*N   = 16000
// total = 2832000

// ---------------------------------------------------------------------------
// Kernel 1: per-box softmax, argmax (first occurrence), score, reg adjust,
// keep init, per-(image,class) count. One wave (64 lanes) per box.
// ---------------------------------------------------------------------------
__global__ __launch_bounds__(256) void prep_kernel(
    const float* __restrict__ nms_reg, const float* __restrict__ rcnn_reg,
    const float* __restrict__ rcnn_cls, const int* __restrict__ reduction,
    float* __restrict__ out, float* __restrict__ scores,
    int* __restrict__ clsArg, int* __restrict__ counts)
{
    int wave = (blockIdx.x * blockDim.x + threadIdx.x) >> 6;
    int lane = threadIdx.x & 63;
    if (wave >= BN) return;
    int b = wave / N_;

    const float* lg = rcnn_cls + (size_t)wave * C_;
    float x0 = lg[lane];
    float x1 = (lane < C_ - 64) ? lg[lane + 64] : -INFINITY;

    // max reduce
    float m = fmaxf(x0, x1);
    for (int off = 32; off; off >>= 1) m = fmaxf(m, __shfl_xor(m, off, 64));

    float e0 = expf(x0 - m);
    float e1 = (lane < C_ - 64) ? expf(x1 - m) : 0.0f;
    float s = e0 + e1;
    for (int off = 32; off; off >>= 1) s += __shfl_xor(s, off, 64);

    float p0 = e0 / s;
    float p1 = e1 / s;

    float* probs = out + O3 + (size_t)wave * C_;
    probs[lane] = p0;
    if (lane < C_ - 64) probs[lane + 64] = p1;

    // argmax of probs, first occurrence (lexicographic: larger value, then smaller idx)
    float v = p0; int idx = lane;
    if (lane < C_ - 64 && p1 > p0) { v = p1; idx = lane + 64; }
    for (int off = 32; off; off >>= 1) {
        float ov = __shfl_xor(v, off, 64);
        int   oi = __shfl_xor(idx, off, 64);
        if (ov > v || (ov == v && oi < idx)) { v = ov; idx = oi; }
    }

    // rcnn_reg_adj: rcnn_reg + round(nms_reg*red)/red  (floor for tl, ceil for br)
    if (lane < 4) {
        float red = (float)reduction[0];
        float nr = nms_reg[(size_t)wave * 4 + lane];
        float t = nr * red;
        float r = (lane < 2) ? floorf(t) : ceilf(t);
        float adj = rcnn_reg[(size_t)wave * 4 + lane] + r / red;
        out[O2 + (size_t)wave * 4 + lane] = adj;
    }

    if (lane == 0) {
        scores[wave] = v;
        clsArg[wave] = idx;
        out[O6 + wave] = 0.0f;               // keep init (nms sets kept ones to 1)
        if (idx != 0) atomicAdd(&counts[b * C_ + idx], 1);
    }
}

// ---------------------------------------------------------------------------
// Kernel 2: per-image exclusive prefix sum over 81 class counts (tiny).
// ---------------------------------------------------------------------------
__global__ void prefix_kernel(const int* __restrict__ counts, int* __restrict__ starts)
{
    int b = threadIdx.x;
    if (b < B_) {
        int run = 0;
        for (int c = 0; c < C_; c++) { starts[b * C_ + c] = run; run += counts[b * C_ + c]; }
    }
}

// ---------------------------------------------------------------------------
// Kernel 3: scatter box indices into class-grouped lists (unordered).
// ---------------------------------------------------------------------------
__global__ __launch_bounds__(256) void scatter_kernel(
    const int* __restrict__ clsArg, const int* __restrict__ starts,
    int* __restrict__ cursor, int* __restrict__ grouped)
{
    int box = blockIdx.x * blockDim.x + threadIdx.x;
    if (box >= BN) return;
    int c = clsArg[box];
    if (c == 0) return;
    int b = box / N_;
    int pos = atomicAdd(&cursor[b * C_ + c], 1);
    grouped[b * N_ + starts[b * C_ + c] + pos] = box;   // global box index b*N+n
}

// ---------------------------------------------------------------------------
// Kernel 4: sort each class list by (score desc, box idx asc) via rank
// counting — deterministic, matches stable argsort of -score restricted to
// class. One wave per (image,class); O(k^2/64).
// ---------------------------------------------------------------------------
__global__ __launch_bounds__(64) void sort_kernel(
    const int* __restrict__ counts, const int* __restrict__ starts,
    const int* __restrict__ grouped, const float* __restrict__ scores,
    int* __restrict__ sorted)
{
    int b = blockIdx.x / C_, c = blockIdx.x % C_;
    if (c == 0) return;
    int k = counts[b * C_ + c];
    if (k == 0) return;
    int base = b * N_ + starts[b * C_ + c];
    for (int t = threadIdx.x; t < k; t += 64) {
        int mybox = grouped[base + t];
        float mys = scores[mybox];
        int rank = 0;
        for (int j = 0; j < k; j++) {
            int ob = grouped[base + j];
            float os = scores[ob];
            rank += (os > mys) || (os == mys && ob < mybox);
        }
        sorted[base + rank] = mybox;
    }
}

// ---------------------------------------------------------------------------
// Kernel 5: greedy NMS within one class. One wave per (image,class).
// keep bits live in per-lane registers (lane l owns positions l, l+64, ...).
// Exactly replicates reference IoU arithmetic in f32 on class-offset coords.
// ---------------------------------------------------------------------------
__global__ __launch_bounds__(64) void nms_kernel(
    const int* __restrict__ counts, const int* __restrict__ starts,
    const int* __restrict__ sorted, const float* __restrict__ boxes4 /* = out+O2 */,
    float* __restrict__ keepF /* = out+O6 */)
{
    int b = blockIdx.x / C_, c = blockIdx.x % C_;
    if (c == 0) return;
    int k = counts[b * C_ + c];
    if (k == 0) return;
    int base = b * N_ + starts[b * C_ + c];
    int lane = threadIdx.x;
    float off = (float)c * 100000.0f;   // exact (integer < 2^23)

    // cache chunk-0 box (covers k<=64, the overwhelmingly common case)
    float t0 = 0, l0 = 0, bb0 = 0, r0 = 0, a0 = 0;
    if (lane < k) {
        int bx = sorted[base + lane];
        const float* p = boxes4 + (size_t)bx * 4;
        t0 = p[0] + off; l0 = p[1] + off; bb0 = p[2] + off; r0 = p[3] + off;
        a0 = (bb0 - t0) * (r0 - l0);
    }

    int nch = (k + 63) >> 6;            // <= 32 (k <= 2000)
    unsigned int keepm = 0;
    for (int ch = 0; ch < nch; ch++) if (ch * 64 + lane < k) keepm |= (1u << ch);

    for (int i = 0; i < k; i++) {
        int ich = i >> 6, il = i & 63;
        unsigned int wi = __shfl(keepm, il, 64);
        if (!((wi >> ich) & 1)) continue;           // wave-uniform

        float ti, li, bi, ri, ai;
        if (ich == 0) {
            ti = __shfl(t0, il, 64); li = __shfl(l0, il, 64);
            bi = __shfl(bb0, il, 64); ri = __shfl(r0, il, 64);
            ai = __shfl(a0, il, 64);
        } else {
            int bx = sorted[base + i];
            const float* p = boxes4 + (size_t)bx * 4;
            ti = p[0] + off; li = p[1] + off; bi = p[2] + off; ri = p[3] + off;
            ai = (bi - ti) * (ri - li);
        }

        for (int ch = ich; ch < nch; ch++) {
            int j = ch * 64 + lane;
            if (j <= i || j >= k) continue;
            if (!((keepm >> ch) & 1)) continue;
            float tj, lj, bj, rj, aj;
            if (ch == 0) { tj = t0; lj = l0; bj = bb0; rj = r0; aj = a0; }
            else {
                int bx = sorted[base + j];
                const float* p = boxes4 + (size_t)bx * 4;
                tj = p[0] + off; lj = p[1] + off; bj = p[2] + off; rj = p[3] + off;
                aj = (bj - tj) * (rj - lj);
            }
            float it = fmaxf(ti, tj), il2 = fmaxf(li, lj);
            float ib = fminf(bi, bj), ir = fminf(ri, rj);
            float inter = fmaxf(ib - it, 0.0f) * fmaxf(ir - il2, 0.0f);
            float uni = ai + aj - inter;
            float iou = inter / fmaxf(uni, 1e-9f);
            if (iou > 0.5f) keepm &= ~(1u << ch);
        }
    }

    for (int ch = 0; ch < nch; ch++) {
        int j = ch * 64 + lane;
        if (j < k && ((keepm >> ch) & 1)) keepF[sorted[base + j]] = 1.0f;
    }
}

// ---------------------------------------------------------------------------
// Kernel 6: apply keep mask + passthrough copies. One wave per box.
// ---------------------------------------------------------------------------
__global__ __launch_bounds__(256) void mask_kernel(
    const float* __restrict__ nms_reg, const float* __restrict__ nms_cls,
    float* __restrict__ out)
{
    int wave = (blockIdx.x * blockDim.x + threadIdx.x) >> 6;
    int lane = threadIdx.x & 63;
    if (wave >= BN) return;

    bool keep = out[O6 + wave] != 0.0f;   // broadcast read

    const float* probs = out + O3 + (size_t)wave * C_;
    float* co = out + O5 + (size_t)wave * C_;
    co[lane] = keep ? probs[lane] : 0.0f;
    if (lane < C_ - 64) co[lane + 64] = keep ? probs[lane + 64] : 0.0f;

    if (lane < 4) {
        float adj = out[O2 + (size_t)wave * 4 + lane];
        out[O4 + (size_t)wave * 4 + lane] = keep ? adj : 0.0f;
        out[O0 + (size_t)wave * 4 + lane] = nms_reg[(size_t)wave * 4 + lane];
    }
    if (lane < 2) out[O1 + (size_t)wave * 2 + lane] = nms_cls[(size_t)wave * 2 + lane];
}

// ---------------------------------------------------------------------------
extern "C" void kernel_launch(void* const* d_in, const int* in_sizes, int n_in,
                              void* d_out, int out_size, void* d_ws, size_t ws_size,
                              hipStream_t stream)
{
    const float* nms_reg  = (const float*)d_in[0];
    const float* nms_cls  = (const float*)d_in[1];
    const float* rcnn_reg = (const float*)d_in[2];
    const float* rcnn_cls = (const float*)d_in[3];
    const int*   reduction = (const int*)d_in[4];
    float* out = (float*)d_out;

    // workspace layout (ints/floats, 4B): ~264 KB total
    int*   wsi     = (int*)d_ws;
    float* scores  = (float*)d_ws;          // [0, 16000)
    int*   clsArg  = wsi + 16000;           // [16000, 32000)
    int*   counts  = wsi + 32000;           // 648
    int*   starts  = wsi + 32648;           // 648
    int*   cursor  = wsi + 33296;           // 648
    int*   grouped = wsi + 33944;           // 16000
    int*   sorted  = wsi + 49944;           // 16000

    // zero counts/starts/cursor (starts rewritten anyway)
    hipMemsetAsync(counts, 0, (size_t)(33944 - 32000) * 4, stream);

    prep_kernel<<<(BN * 64) / 256, 256, 0, stream>>>(
        nms_reg, rcnn_reg, rcnn_cls, reduction, out, scores, clsArg, counts);
    prefix_kernel<<<1, 64, 0, stream>>>(counts, starts);
    scatter_kernel<<<(BN + 255) / 256, 256, 0, stream>>>(clsArg, starts, cursor, grouped);
    sort_kernel<<<B_ * C_, 64, 0, stream>>>(counts, starts, grouped, scores, sorted);
    nms_kernel<<<B_ * C_, 64, 0, stream>>>(counts, starts, sorted, out + O2, out + O6);
    mask_kernel<<<(BN * 64) / 256, 256, 0, stream>>>(nms_reg, nms_cls, out);
}

// Round 2
// 107.166 us; speedup vs baseline: 1.1169x; 1.1169x over previous
//
#include <hip/hip_runtime.h>
#include <math.h>

// Problem constants (fixed by reference setup_inputs)
constexpr int B_ = 8;
constexpr int N_ = 2000;
constexpr int C_ = 81;
constexpr int BN = B_ * N_;

// d_out flat layout (element offsets), reference return order:
// nms_reg, nms_cls, rcnn_reg_adj, probs, reg_out, cls_out, keep
constexpr int O0 = 0;                 // nms_reg      B*N*4 = 64000
constexpr int O1 = 64000;             // nms_cls      B*N*2 = 32000
constexpr int O2 = 96000;             // rcnn_reg_adj B*N*4 = 64000
constexpr int O3 = 160000;            // probs        B*N*81 = 1296000
constexpr int O4 = 1456000;           // reg_out      B*N*4 = 64000
constexpr int O5 = 1520000;           // cls_out      B*N*81 = 1296000
constexpr int O6 = 2816000;           // keep         B*N   = 16000

// ---------------------------------------------------------------------------
// Kernel 1: per-box softmax, argmax (first occurrence), score, reg adjust,
// keep init. One wave (64 lanes) per box. Also does the nms_reg/nms_cls
// passthrough copies with coalesced float4 on the first blocks.
// ---------------------------------------------------------------------------
__global__ __launch_bounds__(256) void prep_kernel(
    const float* __restrict__ nms_reg, const float* __restrict__ nms_cls,
    const float* __restrict__ rcnn_reg, const float* __restrict__ rcnn_cls,
    const int* __restrict__ reduction,
    float* __restrict__ out, float* __restrict__ scores, int* __restrict__ clsArg)
{
    int gid  = blockIdx.x * blockDim.x + threadIdx.x;
    int wave = gid >> 6;
    int lane = threadIdx.x & 63;
    if (wave >= BN) return;

    // coalesced passthrough copies (first 16000 / 8000 threads)
    if (gid < BN) {               // nms_reg: 64000 floats = 16000 float4
        ((float4*)(out + O0))[gid] = ((const float4*)nms_reg)[gid];
        if (gid < BN / 2)         // nms_cls: 32000 floats = 8000 float4
            ((float4*)(out + O1))[gid] = ((const float4*)nms_cls)[gid];
    }

    const float* lg = rcnn_cls + (size_t)wave * C_;
    float x0 = lg[lane];
    float x1 = (lane < C_ - 64) ? lg[lane + 64] : -INFINITY;

    float m = fmaxf(x0, x1);
    for (int off = 32; off; off >>= 1) m = fmaxf(m, __shfl_xor(m, off, 64));

    float e0 = expf(x0 - m);
    float e1 = (lane < C_ - 64) ? expf(x1 - m) : 0.0f;
    float s = e0 + e1;
    for (int off = 32; off; off >>= 1) s += __shfl_xor(s, off, 64);

    float p0 = e0 / s;
    float p1 = e1 / s;

    float* probs = out + O3 + (size_t)wave * C_;
    probs[lane] = p0;
    if (lane < C_ - 64) probs[lane + 64] = p1;

    // argmax, first occurrence (larger value wins; tie -> smaller index)
    float v = p0; int idx = lane;
    if (lane < C_ - 64 && p1 > p0) { v = p1; idx = lane + 64; }
    for (int off = 32; off; off >>= 1) {
        float ov = __shfl_xor(v, off, 64);
        int   oi = __shfl_xor(idx, off, 64);
        if (ov > v || (ov == v && oi < idx)) { v = ov; idx = oi; }
    }

    // rcnn_reg_adj = rcnn_reg + (floor/ceil(nms_reg*red))/red
    if (lane < 4) {
        float red = (float)reduction[0];
        float t = nms_reg[(size_t)wave * 4 + lane] * red;
        float r = (lane < 2) ? floorf(t) : ceilf(t);
        out[O2 + (size_t)wave * 4 + lane] =
            rcnn_reg[(size_t)wave * 4 + lane] + r / red;
    }

    if (lane == 0) {
        scores[wave] = v;
        clsArg[wave] = idx;
        out[O6 + wave] = 0.0f;   // keep init; classnms sets kept ones to 1
    }
}

// ---------------------------------------------------------------------------
// Kernel 2: fused gather + sort + greedy NMS. One wave per (image, class>0).
// Gather: scan the image's 2000 clsArg entries with ballot compaction into
// LDS. Sort: rank-count by (score desc, box idx asc) — identical result to
// stable argsort of -score restricted to the class. NMS: keep bits in
// registers, exact replication of reference IoU arithmetic on offset coords.
// ---------------------------------------------------------------------------
__global__ __launch_bounds__(64) void classnms_kernel(
    const int* __restrict__ clsArg, const float* __restrict__ scores,
    const float* __restrict__ boxes4 /* = out+O2 */,
    float* __restrict__ keepF /* = out+O6 */)
{
    __shared__ int   list[N_];
    __shared__ float sc[N_];
    __shared__ int   srt[N_];

    int b = blockIdx.x / (C_ - 1);
    int c = blockIdx.x % (C_ - 1) + 1;
    int lane = threadIdx.x;

    // ---- gather ----
    int k = 0;
    for (int it = 0; it < (N_ + 63) / 64; it++) {
        int n = it * 64 + lane;
        bool m = false;
        float sv = 0.0f;
        if (n < N_) {
            m  = (clsArg[b * N_ + n] == c);
            sv = scores[b * N_ + n];        // coalesced; used only if m
        }
        unsigned long long bal = __ballot(m);
        if (m) {
            int pos = k + __popcll(bal & ((1ull << lane) - 1ull));
            list[pos] = n;
            sc[pos]   = sv;
        }
        k += __popcll(bal);                 // wave-uniform
    }
    __syncthreads();
    if (k == 0) return;

    // ---- rank sort ----
    for (int t = lane; t < k; t += 64) {
        int   my  = list[t];
        float mys = sc[t];
        int rank = 0;
        for (int j = 0; j < k; j++) {
            float os = sc[j];
            rank += (os > mys) || (os == mys && list[j] < my);
        }
        srt[rank] = my;
    }
    __syncthreads();

    // ---- NMS ----
    float off = (float)c * 100000.0f;       // exact (integer < 2^23)

    float t0 = 0, l0 = 0, bb0 = 0, r0 = 0, a0 = 0;
    if (lane < k) {
        const float* p = boxes4 + (size_t)(b * N_ + srt[lane]) * 4;
        t0 = p[0] + off; l0 = p[1] + off; bb0 = p[2] + off; r0 = p[3] + off;
        a0 = (bb0 - t0) * (r0 - l0);
    }

    int nch = (k + 63) >> 6;
    unsigned int keepm = 0;
    for (int ch = 0; ch < nch; ch++) if (ch * 64 + lane < k) keepm |= (1u << ch);

    for (int i = 0; i < k; i++) {
        int ich = i >> 6, il = i & 63;
        unsigned int wi = __shfl(keepm, il, 64);
        if (!((wi >> ich) & 1)) continue;   // wave-uniform: i was suppressed

        float ti, li, bi, ri, ai;
        if (ich == 0) {
            ti = __shfl(t0, il, 64); li = __shfl(l0, il, 64);
            bi = __shfl(bb0, il, 64); ri = __shfl(r0, il, 64);
            ai = __shfl(a0, il, 64);
        } else {
            const float* p = boxes4 + (size_t)(b * N_ + srt[i]) * 4;
            ti = p[0] + off; li = p[1] + off; bi = p[2] + off; ri = p[3] + off;
            ai = (bi - ti) * (ri - li);
        }

        for (int ch = ich; ch < nch; ch++) {
            int j = ch * 64 + lane;
            if (j <= i || j >= k) continue;
            if (!((keepm >> ch) & 1)) continue;
            float tj, lj, bj, rj, aj;
            if (ch == 0) { tj = t0; lj = l0; bj = bb0; rj = r0; aj = a0; }
            else {
                const float* p = boxes4 + (size_t)(b * N_ + srt[j]) * 4;
                tj = p[0] + off; lj = p[1] + off; bj = p[2] + off; rj = p[3] + off;
                aj = (bj - tj) * (rj - lj);
            }
            float it2 = fmaxf(ti, tj), il2 = fmaxf(li, lj);
            float ib = fminf(bi, bj), ir = fminf(ri, rj);
            float inter = fmaxf(ib - it2, 0.0f) * fmaxf(ir - il2, 0.0f);
            float uni = ai + aj - inter;
            if (inter / fmaxf(uni, 1e-9f) > 0.5f) keepm &= ~(1u << ch);
        }
    }

    for (int ch = 0; ch < nch; ch++) {
        int j = ch * 64 + lane;
        if (j < k && ((keepm >> ch) & 1)) keepF[b * N_ + srt[j]] = 1.0f;
    }
}

// ---------------------------------------------------------------------------
// Kernel 3: apply keep mask. One wave per box.
// ---------------------------------------------------------------------------
__global__ __launch_bounds__(256) void mask_kernel(float* __restrict__ out)
{
    int wave = (blockIdx.x * blockDim.x + threadIdx.x) >> 6;
    int lane = threadIdx.x & 63;
    if (wave >= BN) return;

    bool keep = out[O6 + wave] != 0.0f;     // broadcast read

    const float* probs = out + O3 + (size_t)wave * C_;
    float* co = out + O5 + (size_t)wave * C_;
    co[lane] = keep ? probs[lane] : 0.0f;
    if (lane < C_ - 64) co[lane + 64] = keep ? probs[lane + 64] : 0.0f;

    if (lane < 4) {
        float adj = out[O2 + (size_t)wave * 4 + lane];
        out[O4 + (size_t)wave * 4 + lane] = keep ? adj : 0.0f;
    }
}

// ---------------------------------------------------------------------------
extern "C" void kernel_launch(void* const* d_in, const int* in_sizes, int n_in,
                              void* d_out, int out_size, void* d_ws, size_t ws_size,
                              hipStream_t stream)
{
    const float* nms_reg   = (const float*)d_in[0];
    const float* nms_cls   = (const float*)d_in[1];
    const float* rcnn_reg  = (const float*)d_in[2];
    const float* rcnn_cls  = (const float*)d_in[3];
    const int*   reduction = (const int*)d_in[4];
    float* out = (float*)d_out;

    float* scores = (float*)d_ws;                // 16000 floats
    int*   clsArg = (int*)d_ws + 16000;          // 16000 ints

    prep_kernel<<<(BN * 64) / 256, 256, 0, stream>>>(
        nms_reg, nms_cls, rcnn_reg, rcnn_cls, reduction, out, scores, clsArg);
    classnms_kernel<<<B_ * (C_ - 1), 64, 0, stream>>>(
        clsArg, scores, out + O2, out + O6);
    mask_kernel<<<(BN * 64) / 256, 256, 0, stream>>>(out);
}

// Round 3
// 100.579 us; speedup vs baseline: 1.1901x; 1.0655x over previous
//
#include <hip/hip_runtime.h>
#include <math.h>

// Problem constants (fixed by reference setup_inputs)
constexpr int B_ = 8;
constexpr int N_ = 2000;
constexpr int C_ = 81;
constexpr int BN = B_ * N_;

// d_out flat layout (element offsets), reference return order:
// nms_reg, nms_cls, rcnn_reg_adj, probs, reg_out, cls_out, keep
constexpr int O0 = 0;                 // nms_reg      B*N*4 = 64000
constexpr int O1 = 64000;             // nms_cls      B*N*2 = 32000
constexpr int O2 = 96000;             // rcnn_reg_adj B*N*4 = 64000
constexpr int O3 = 160000;            // probs        B*N*81 = 1296000
constexpr int O4 = 1456000;           // reg_out      B*N*4 = 64000
constexpr int O5 = 1520000;           // cls_out      B*N*81 = 1296000
constexpr int O6 = 2816000;           // keep         B*N   = 16000

// ---------------------------------------------------------------------------
// Kernel 1: per-box softmax, argmax (first occurrence on probs), score,
// reg adjust, keep init. One wave per box. Class-0 boxes (never kept) get
// their cls_out/reg_out rows zeroed here. Passthrough copies grid-strided
// over the first threads as float4.
// ---------------------------------------------------------------------------
__global__ __launch_bounds__(256) void prep_kernel(
    const float* __restrict__ nms_reg, const float* __restrict__ nms_cls,
    const float* __restrict__ rcnn_reg, const float* __restrict__ rcnn_cls,
    const int* __restrict__ reduction,
    float* __restrict__ out, float* __restrict__ scores, int* __restrict__ clsArg)
{
    int gid  = blockIdx.x * blockDim.x + threadIdx.x;
    int wave = gid >> 6;
    int lane = threadIdx.x & 63;
    if (wave >= BN) return;

    // coalesced passthrough copies: nms_reg 16000 float4, nms_cls 8000 float4
    if (gid < 16000) {
        ((float4*)(out + O0))[gid] = ((const float4*)nms_reg)[gid];
    } else if (gid < 24000) {
        int g = gid - 16000;
        ((float4*)(out + O1))[g] = ((const float4*)nms_cls)[g];
    }

    const float* lg = rcnn_cls + (size_t)wave * C_;
    float x0 = lg[lane];
    float x1 = (lane < C_ - 64) ? lg[lane + 64] : -INFINITY;

    float m = fmaxf(x0, x1);
    for (int off = 32; off; off >>= 1) m = fmaxf(m, __shfl_xor(m, off, 64));

    float e0 = expf(x0 - m);
    float e1 = (lane < C_ - 64) ? expf(x1 - m) : 0.0f;
    float s = e0 + e1;
    for (int off = 32; off; off >>= 1) s += __shfl_xor(s, off, 64);

    float p0 = e0 / s;
    float p1 = e1 / s;

    float* probs = out + O3 + (size_t)wave * C_;
    probs[lane] = p0;
    if (lane < C_ - 64) probs[lane + 64] = p1;

    // argmax on probs, first occurrence (larger value; tie -> smaller index)
    float v = p0; int idx = lane;
    if (lane < C_ - 64 && p1 > p0) { v = p1; idx = lane + 64; }
    for (int off = 32; off; off >>= 1) {
        float ov = __shfl_xor(v, off, 64);
        int   oi = __shfl_xor(idx, off, 64);
        if (ov > v || (ov == v && oi < idx)) { v = ov; idx = oi; }
    }

    // rcnn_reg_adj = rcnn_reg + (floor/ceil(nms_reg*red))/red
    if (lane < 4) {
        float red = (float)reduction[0];
        float t = nms_reg[(size_t)wave * 4 + lane] * red;
        float r = (lane < 2) ? floorf(t) : ceilf(t);
        out[O2 + (size_t)wave * 4 + lane] =
            rcnn_reg[(size_t)wave * 4 + lane] + r / red;
    }

    // class-0 boxes are never kept: zero their output rows now
    if (idx == 0) {
        float* co = out + O5 + (size_t)wave * C_;
        co[lane] = 0.0f;
        if (lane < C_ - 64) co[lane + 64] = 0.0f;
        if (lane < 4) out[O4 + (size_t)wave * 4 + lane] = 0.0f;
    }

    if (lane == 0) {
        scores[wave] = v;
        clsArg[wave] = idx;
        out[O6 + wave] = 0.0f;   // keep init; classnms sets kept ones to 1
    }
}

// ---------------------------------------------------------------------------
// Kernel 2: fused gather + sort + greedy NMS + output write.
// One block (256 threads) per (image, class>0).
//   gather: 4 waves scan 500-entry strips, ballot-compact into LDS (order
//           irrelevant: rank-sort uses explicit (score desc, idx asc) key)
//   sort:   256-thread rank counting, deterministic == stable argsort
//   nms:    wave 0, keep bits in registers, exact reference IoU arithmetic
//   write:  256 threads write keep / reg_out / cls_out for member boxes
// ---------------------------------------------------------------------------
__global__ __launch_bounds__(256) void classnms_kernel(
    const int* __restrict__ clsArg, const float* __restrict__ scores,
    float* __restrict__ out)
{
    __shared__ int   list[N_];   // gather ids; reused as keep flags (sorted order)
    __shared__ float sc[N_];
    __shared__ int   srt[N_];
    __shared__ int   cnt;

    int b = blockIdx.x / (C_ - 1);
    int c = blockIdx.x % (C_ - 1) + 1;
    int tid  = threadIdx.x;
    int lane = tid & 63;
    int w    = tid >> 6;         // wave id 0..3

    if (tid == 0) cnt = 0;
    __syncthreads();

    // ---- gather: wave w scans strip [w*500, (w+1)*500) ----
    const int STRIP = N_ / 4;    // 500
    for (int it = 0; it < (STRIP + 63) / 64; it++) {
        int n = w * STRIP + it * 64 + lane;
        bool m = false;
        float sv = 0.0f;
        if (n < (w + 1) * STRIP) {
            m  = (clsArg[b * N_ + n] == c);
            sv = scores[b * N_ + n];
        }
        unsigned long long bal = __ballot(m);
        int nset = __popcll(bal);
        int base = 0;
        if (lane == 0 && nset) base = atomicAdd(&cnt, nset);
        base = __shfl(base, 0, 64);
        if (m) {
            int pos = base + __popcll(bal & ((1ull << lane) - 1ull));
            list[pos] = n;
            sc[pos]   = sv;
        }
    }
    __syncthreads();
    int k = cnt;
    if (k == 0) return;          // uniform exit

    // ---- rank sort: (score desc, idx asc) ----
    for (int t = tid; t < k; t += 256) {
        int   my  = list[t];
        float mys = sc[t];
        int rank = 0;
        for (int j = 0; j < k; j++) {
            float os = sc[j];
            rank += (os > mys) || (os == mys && list[j] < my);
        }
        srt[rank] = my;
    }
    __syncthreads();

    // ---- NMS on wave 0; flags into list[] (sorted order) ----
    const float* boxes4 = out + O2;
    if (w == 0) {
        float off = (float)c * 100000.0f;    // exact integer < 2^23

        float t0 = 0, l0 = 0, bb0 = 0, r0 = 0, a0 = 0;
        if (lane < k) {
            const float* p = boxes4 + (size_t)(b * N_ + srt[lane]) * 4;
            t0 = p[0] + off; l0 = p[1] + off; bb0 = p[2] + off; r0 = p[3] + off;
            a0 = (bb0 - t0) * (r0 - l0);
        }

        int nch = (k + 63) >> 6;
        unsigned int keepm = 0;
        for (int ch = 0; ch < nch; ch++) if (ch * 64 + lane < k) keepm |= (1u << ch);

        for (int i = 0; i < k; i++) {
            int ich = i >> 6, il = i & 63;
            unsigned int wi = __shfl(keepm, il, 64);
            if (!((wi >> ich) & 1)) continue;    // wave-uniform

            float ti, li, bi, ri, ai;
            if (ich == 0) {
                ti = __shfl(t0, il, 64); li = __shfl(l0, il, 64);
                bi = __shfl(bb0, il, 64); ri = __shfl(r0, il, 64);
                ai = __shfl(a0, il, 64);
            } else {
                const float* p = boxes4 + (size_t)(b * N_ + srt[i]) * 4;
                ti = p[0] + off; li = p[1] + off; bi = p[2] + off; ri = p[3] + off;
                ai = (bi - ti) * (ri - li);
            }

            for (int ch = ich; ch < nch; ch++) {
                int j = ch * 64 + lane;
                if (j <= i || j >= k) continue;
                if (!((keepm >> ch) & 1)) continue;
                float tj, lj, bj, rj, aj;
                if (ch == 0) { tj = t0; lj = l0; bj = bb0; rj = r0; aj = a0; }
                else {
                    const float* p = boxes4 + (size_t)(b * N_ + srt[j]) * 4;
                    tj = p[0] + off; lj = p[1] + off; bj = p[2] + off; rj = p[3] + off;
                    aj = (bj - tj) * (rj - lj);
                }
                float it2 = fmaxf(ti, tj), il2 = fmaxf(li, lj);
                float ib = fminf(bi, bj), ir = fminf(ri, rj);
                float inter = fmaxf(ib - it2, 0.0f) * fmaxf(ir - il2, 0.0f);
                float uni = ai + aj - inter;
                if (inter / fmaxf(uni, 1e-9f) > 0.5f) keepm &= ~(1u << ch);
            }
        }

        for (int ch = 0; ch < nch; ch++) {
            int j = ch * 64 + lane;
            if (j < k) list[j] = (keepm >> ch) & 1;
        }
    }
    __syncthreads();

    // ---- output write for member boxes ----
    // keep flag + reg_out (4 floats each)
    for (int p = tid; p < k; p += 256) {
        int g = b * N_ + srt[p];
        int kept = list[p];
        out[O6 + g] = kept ? 1.0f : 0.0f;
        float4 adj = ((const float4*)(out + O2))[g];
        ((float4*)(out + O4))[g] = kept ? adj : float4{0.f, 0.f, 0.f, 0.f};
    }
    // cls_out rows (k * 81 elements)
    for (int idx = tid; idx < k * C_; idx += 256) {
        int p = idx / C_, e = idx - p * C_;
        int g = b * N_ + srt[p];
        out[O5 + (size_t)g * C_ + e] =
            list[p] ? out[O3 + (size_t)g * C_ + e] : 0.0f;
    }
}

// ---------------------------------------------------------------------------
extern "C" void kernel_launch(void* const* d_in, const int* in_sizes, int n_in,
                              void* d_out, int out_size, void* d_ws, size_t ws_size,
                              hipStream_t stream)
{
    const float* nms_reg   = (const float*)d_in[0];
    const float* nms_cls   = (const float*)d_in[1];
    const float* rcnn_reg  = (const float*)d_in[2];
    const float* rcnn_cls  = (const float*)d_in[3];
    const int*   reduction = (const int*)d_in[4];
    float* out = (float*)d_out;

    float* scores = (float*)d_ws;                // 16000 floats
    int*   clsArg = (int*)d_ws + 16000;          // 16000 ints

    prep_kernel<<<(BN * 64) / 256, 256, 0, stream>>>(
        nms_reg, nms_cls, rcnn_reg, rcnn_cls, reduction, out, scores, clsArg);
    classnms_kernel<<<B_ * (C_ - 1), 256, 0, stream>>>(clsArg, scores, out);
}